// Round 5
// baseline (198.718 us; speedup 1.0000x reference)
//
#include <hip/hip_runtime.h>
#include <hip/hip_bf16.h>
#include <hip/hip_fp16.h>

#define L_SEQ 2048
#define D_MODEL 512
#define NH 8
#define HD 64
#define EPSF 1e-5f

// u f16 layout: [512 ch][2560], logical s at col 256+s; margins zeroed.
#define UPAD 2560
#define UOFF 256
// filter LDS: 8 phase copies, stride 2120 f16 (=1060 words, == 4 mod 32 -> 2-way-free banks)
#define XLEN 2112
#define XPAD 2120

typedef __attribute__((ext_vector_type(8))) short short8;
typedef __attribute__((ext_vector_type(8))) _Float16 half8;
typedef __attribute__((ext_vector_type(4))) _Float16 half4v;
typedef __attribute__((ext_vector_type(4))) float f32x4;

union bfu { ushort u; __hip_bfloat16 b; };

// ---------------- prep: fp32->bf16 (vectorized x4) + zero u16 margins ----------------
// units: [0,262144) x; [262144,524288) sb; [524288,851968) weights; [851968,917504) margins
__global__ __launch_bounds__(256) void prep_kernel(const float* __restrict__ x,
    const float* __restrict__ sb, const float* __restrict__ wq, const float* __restrict__ wk,
    const float* __restrict__ wv, const float* __restrict__ td, const float* __restrict__ wo,
    __hip_bfloat16* __restrict__ xb, __hip_bfloat16* __restrict__ sbb,
    __hip_bfloat16* __restrict__ wqb, __hip_bfloat16* __restrict__ wkb,
    __hip_bfloat16* __restrict__ wvb, __hip_bfloat16* __restrict__ tdb,
    __hip_bfloat16* __restrict__ wob,
    _Float16* __restrict__ ku16, _Float16* __restrict__ vu16)
{
  int i = blockIdx.x * 256 + threadIdx.x;
  if (i < 851968) {
    const float* s;
    __hip_bfloat16* d;
    int r;
    if (i < 262144) { s = x; d = xb; r = i; }
    else if (i < 524288) { s = sb; d = sbb; r = i - 262144; }
    else {
      int j = i - 524288;
      int w = j >> 16;
      r = j & 65535;
      s = (w == 0) ? wq : (w == 1) ? wk : (w == 2) ? wv : (w == 3) ? td : wo;
      d = (w == 0) ? wqb : (w == 1) ? wkb : (w == 2) ? wvb : (w == 3) ? tdb : wob;
    }
    float4 v = *(const float4*)(s + r * 4);
    ushort4 o;
    { bfu t; t.b = __float2bfloat16(v.x); o.x = t.u; }
    { bfu t; t.b = __float2bfloat16(v.y); o.y = t.u; }
    { bfu t; t.b = __float2bfloat16(v.z); o.z = t.u; }
    { bfu t; t.b = __float2bfloat16(v.w); o.w = t.u; }
    *(ushort4*)((__hip_bfloat16*)d + r * 4) = o;
  } else if (i < 917504) {
    int t = i - 851968;
    int arr = t >> 15;
    int rem = t & 32767;
    int row = rem >> 6;
    int cc = rem & 63;
    int col = (cc < 32) ? cc * 8 : 2304 + (cc - 32) * 8;
    _Float16* base = arr ? vu16 : ku16;
    *(int4*)(base + (size_t)row * UPAD + col) = int4{0, 0, 0, 0};
  }
}

// ---------------- batched GEMM: q,k,v,filters; l2norm + f16 pad-write for k,v ----------------
__global__ __launch_bounds__(256) void gemm4_kernel(
    const __hip_bfloat16* __restrict__ xb, const __hip_bfloat16* __restrict__ sbb,
    const __hip_bfloat16* __restrict__ wqb, const __hip_bfloat16* __restrict__ wkb,
    const __hip_bfloat16* __restrict__ wvb, const __hip_bfloat16* __restrict__ tdb,
    const float* __restrict__ bq, const float* __restrict__ bk,
    const float* __restrict__ bv, const float* __restrict__ btd,
    float* __restrict__ qout, float* __restrict__ fT,
    _Float16* __restrict__ ku16, _Float16* __restrict__ vu16)
{
  int z = blockIdx.z;
  const __hip_bfloat16* A = (z == 3) ? sbb : xb;
  const __hip_bfloat16* W = (z == 0) ? wqb : (z == 1) ? wkb : (z == 2) ? wvb : tdb;
  const float* bias = (z == 0) ? bq : (z == 1) ? bk : (z == 2) ? bv : btd;
  const int M = L_SEQ, N = D_MODEL, K = D_MODEL;
  int lane = threadIdx.x & 63;
  int wave = threadIdx.x >> 6;
  int m0 = blockIdx.x * 64 + wave * 16;
  int n0 = blockIdx.y * 64;
  int lrow = lane & 15, quad = lane >> 4;
  const __hip_bfloat16* Ap = A + (size_t)(m0 + lrow) * K + quad * 8;
  const __hip_bfloat16* Wp = W + (size_t)(n0 + lrow) * K + quad * 8;
  f32x4 acc[4] = {};
  for (int k0 = 0; k0 < K; k0 += 32) {
    short8 a = *(const short8*)(Ap + k0);
#pragma unroll
    for (int j = 0; j < 4; ++j) {
      short8 b = *(const short8*)(Wp + k0 + (size_t)j * 16 * K);
      acc[j] = __builtin_amdgcn_mfma_f32_16x16x32_bf16(a, b, acc[j], 0, 0, 0);
    }
  }
  float bw[4];
#pragma unroll
  for (int j = 0; j < 4; ++j) bw[j] = bias[n0 + j * 16 + lrow];
  if (z == 0) {
#pragma unroll
    for (int j = 0; j < 4; ++j)
#pragma unroll
      for (int r = 0; r < 4; ++r)
        qout[(size_t)(m0 + quad * 4 + r) * N + n0 + j * 16 + lrow] = acc[j][r] + bw[j];
  } else if (z == 3) {
#pragma unroll
    for (int j = 0; j < 4; ++j) {
      float4 ov = {acc[j][0] + bw[j], acc[j][1] + bw[j], acc[j][2] + bw[j], acc[j][3] + bw[j]};
      *(float4*)(fT + (size_t)(n0 + j * 16 + lrow) * M + m0 + quad * 4) = ov;
    }
  } else {
    float val[4][4];
#pragma unroll
    for (int j = 0; j < 4; ++j)
#pragma unroll
      for (int r = 0; r < 4; ++r) val[j][r] = acc[j][r] + bw[j];
    // l2-normalize over head dim (this block's 64 n-cols = one head)
    float pr[4];
#pragma unroll
    for (int r = 0; r < 4; ++r)
      pr[r] = val[0][r] * val[0][r] + val[1][r] * val[1][r] +
              val[2][r] * val[2][r] + val[3][r] * val[3][r];
#pragma unroll
    for (int off = 1; off < 16; off <<= 1)
#pragma unroll
      for (int r = 0; r < 4; ++r)
        pr[r] += __shfl_xor(pr[r], off, 64);
    _Float16* u16 = (z == 1) ? ku16 : vu16;
#pragma unroll
    for (int r = 0; r < 4; ++r) {
      float inv = 1.f / fmaxf(sqrtf(pr[r]), EPSF);
#pragma unroll
      for (int j = 0; j < 4; ++j) val[j][r] *= inv;
    }
#pragma unroll
    for (int j = 0; j < 4; ++j) {
      half4v pk = {(_Float16)val[j][0], (_Float16)val[j][1],
                   (_Float16)val[j][2], (_Float16)val[j][3]};
      *(half4v*)(u16 + (size_t)(n0 + j * 16 + lrow) * UPAD + UOFF + m0 + quad * 4) = pk;
    }
  }
}

// ---------------- causal conv via MFMA Toeplitz, filter in LDS (f16) ----------------
__global__ __launch_bounds__(256) void conv_kernel(
    const _Float16* __restrict__ ku16, const _Float16* __restrict__ vu16,
    const float* __restrict__ fT, float* __restrict__ oK, float* __restrict__ oV)
{
  __shared__ _Float16 lds_f[8 * XPAD];
  int c = blockIdx.x;
  int tid = threadIdx.x;
  const float* Fc = fT + (size_t)c * L_SEQ;
#pragma unroll
  for (int p = 0; p < 8; ++p) {
#pragma unroll
    for (int t = 0; t < 9; ++t) {
      int xx = tid + t * 256;
      if (xx < XLEN) {
        int j = 2063 - xx - p;
        float v = (j >= 0 && j < L_SEQ) ? Fc[j] : 0.f;
        lds_f[p * XPAD + xx] = (_Float16)v;
      }
    }
  }
  __syncthreads();

  int wave = tid >> 6, lane = tid & 63;
  int pair = wave;
  int l0_lo = 256 * pair;
  int l0_hi = 1792 - l0_lo;
  int mn = lane & 15, quad = lane >> 4;

  const _Float16* puk = ku16 + (size_t)c * UPAD + 16 * mn + 8 * quad;
  const _Float16* puv = vu16 + (size_t)c * UPAD + 16 * mn + 8 * quad;

  int j0c = 2063 - mn;
  int p8 = j0c & 7;
  int xb0 = (j0c - p8) + 8 * quad;
  const _Float16* pf_hi = lds_f + p8 * XPAD + (xb0 - (l0_hi + 256));
  const _Float16* pf_lo = lds_f + p8 * XPAD + (xb0 - (l0_lo + 256));

  int steps_lo = pair * 8 + 9;
  int steps_hi = 65 - pair * 8;
  f32x4 ak_hi = {}, ak_lo = {}, av_hi = {}, av_lo = {};
#pragma unroll 2
  for (int i = 0; i < steps_lo; ++i) {
    half8 bk = *(const half8*)puk;
    half8 bv = *(const half8*)puv;
    half8 fh = *(const half8*)pf_hi;
    half8 fl = *(const half8*)pf_lo;
    puk += 32; puv += 32; pf_hi += 32; pf_lo += 32;
    ak_hi = __builtin_amdgcn_mfma_f32_16x16x32_f16(fh, bk, ak_hi, 0, 0, 0);
    av_hi = __builtin_amdgcn_mfma_f32_16x16x32_f16(fh, bv, av_hi, 0, 0, 0);
    ak_lo = __builtin_amdgcn_mfma_f32_16x16x32_f16(fl, bk, ak_lo, 0, 0, 0);
    av_lo = __builtin_amdgcn_mfma_f32_16x16x32_f16(fl, bv, av_lo, 0, 0, 0);
  }
#pragma unroll 2
  for (int i = steps_lo; i < steps_hi; ++i) {
    half8 bk = *(const half8*)puk;
    half8 bv = *(const half8*)puv;
    half8 fh = *(const half8*)pf_hi;
    puk += 32; puv += 32; pf_hi += 32;
    ak_hi = __builtin_amdgcn_mfma_f32_16x16x32_f16(fh, bk, ak_hi, 0, 0, 0);
    av_hi = __builtin_amdgcn_mfma_f32_16x16x32_f16(fh, bv, av_hi, 0, 0, 0);
  }
  size_t ob = (size_t)c * L_SEQ + 16 * mn + 4 * quad;
  *(float4*)(oK + ob + l0_hi) = float4{ak_hi[0], ak_hi[1], ak_hi[2], ak_hi[3]};
  *(float4*)(oK + ob + l0_lo) = float4{ak_lo[0], ak_lo[1], ak_lo[2], ak_lo[3]};
  *(float4*)(oV + ob + l0_hi) = float4{av_hi[0], av_hi[1], av_hi[2], av_hi[3]};
  *(float4*)(oV + ob + l0_lo) = float4{av_lo[0], av_lo[1], av_lo[2], av_lo[3]};
}

// ---------------- fused gate + partials per (h, chunk) ----------------
__global__ __launch_bounds__(256) void gatepart_kernel(const float* __restrict__ kf,
    const float* __restrict__ vf, const float* __restrict__ wgz_w,
    const float* __restrict__ wgz_b, const float* __restrict__ kvs,
    float* __restrict__ g, float* __restrict__ A, float* __restrict__ gsum)
{
  __shared__ float MT[64][68];
  __shared__ float kb[64][68];
  __shared__ float vb[64][68];
  __shared__ float yb[64][68];
  __shared__ float part[4][64];
  __shared__ float gl[64];
  int h = blockIdx.y, ch = blockIdx.x;
  int t0 = ch * 64, tid = threadIdx.x;
#pragma unroll
  for (int k = 0; k < 16; ++k) {
    int idx = tid + k * 256;
    int a = idx >> 6, b = idx & 63;
    MT[b][a] = wgz_w[idx] * kvs[idx];
    kb[a][b] = kf[(size_t)(h * 64 + a) * L_SEQ + t0 + b];
    vb[a][b] = vf[(size_t)(h * 64 + a) * L_SEQ + t0 + b];
  }
  __syncthreads();
  int lg = tid & 15, dg = tid >> 4;
  {
    float acc[4][4] = {};
    for (int e = 0; e < 64; ++e) {
      float4 mv4 = *(const float4*)(&MT[e][dg * 4]);
      float4 kv4 = *(const float4*)(&kb[e][lg * 4]);
      float mvv[4] = {mv4.x, mv4.y, mv4.z, mv4.w};
      float kvv[4] = {kv4.x, kv4.y, kv4.z, kv4.w};
#pragma unroll
      for (int r = 0; r < 4; ++r)
#pragma unroll
        for (int j = 0; j < 4; ++j)
          acc[r][j] = fmaf(mvv[r], kvv[j], acc[r][j]);
    }
#pragma unroll
    for (int r = 0; r < 4; ++r)
#pragma unroll
      for (int j = 0; j < 4; ++j)
        yb[dg * 4 + r][lg * 4 + j] = acc[r][j];
  }
  __syncthreads();
  {
    int l = tid & 63, p = tid >> 6;
    float s = 0.f;
#pragma unroll
    for (int dd = 0; dd < 16; ++dd)
      s = fmaf(yb[p * 16 + dd][l], vb[p * 16 + dd][l], s);
    part[p][l] = s;
  }
  __syncthreads();
  if (tid < 64) {
    float logit = part[0][tid] + part[1][tid] + part[2][tid] + part[3][tid] + wgz_b[0];
    float rl = fmaxf(logit, 0.f);
    float gv = rl * rl + EPSF;
    g[h * L_SEQ + t0 + tid] = gv;
    gl[tid] = gv;
  }
  __syncthreads();
  int eg = tid & 15, dg2 = tid >> 4;
  float acc[4][4] = {};
  for (int t = 0; t < 64; ++t) {
    float gt = gl[t];
    float kv4[4], vv4[4];
#pragma unroll
    for (int j = 0; j < 4; ++j) kv4[j] = kb[eg * 4 + j][t] * gt;
#pragma unroll
    for (int r = 0; r < 4; ++r) vv4[r] = vb[dg2 * 4 + r][t];
#pragma unroll
    for (int r = 0; r < 4; ++r)
#pragma unroll
      for (int j = 0; j < 4; ++j)
        acc[r][j] = fmaf(vv4[r], kv4[j], acc[r][j]);
  }
  float* Ap = A + ((size_t)(h * 32 + ch)) * 4096;
#pragma unroll
  for (int r = 0; r < 4; ++r)
#pragma unroll
    for (int j = 0; j < 4; ++j)
      Ap[(dg2 * 4 + r) * 64 + eg * 4 + j] = acc[r][j];
  if (tid == 0) {
    float s = 0.f;
    for (int t = 0; t < 64; ++t) s += gl[t];
    gsum[h * 32 + ch] = s;
  }
}

// ---------------- attention: fused chunk-prefix + carry + in-chunk quadratic ----------------
// Sprev computed in-block: sum of Abuf[h, 0..ch-1]; Gprev from raw gsum via shuffle.
__global__ __launch_bounds__(256) void attn_kernel(const float* __restrict__ q,
    const float* __restrict__ kf, const float* __restrict__ vf, const float* __restrict__ g,
    const float* __restrict__ Abuf, const float* __restrict__ gsum,
    __hip_bfloat16* __restrict__ sp)
{
  __shared__ float qT[64][68];
  __shared__ float SW[64][69];
  __shared__ float vb[64][68];
  __shared__ float kb[64][69];
  __shared__ float part2[16][64];
  __shared__ float gl[64], Gs[64], rsq[64];
  int h = blockIdx.y, ch = blockIdx.x;
  int t0 = ch * 64, tid = threadIdx.x;
#pragma unroll
  for (int k = 0; k < 16; ++k) {
    int idx = tid + k * 256;
    int a = idx >> 6, b = idx & 63;
    qT[b][a] = q[(size_t)(t0 + a) * D_MODEL + h * 64 + b];
    vb[a][b] = vf[(size_t)(h * 64 + a) * L_SEQ + t0 + b];
    kb[a][b] = kf[(size_t)(h * 64 + a) * L_SEQ + t0 + b];
  }
  // chunk prefix: SW[d][e] = sum_{c<ch} Abuf[h,c][d*64+e]
  {
    float4 s[4] = {};
    const float4* Ab = (const float4*)(Abuf + ((size_t)h * 32) * 4096);
    for (int c = 0; c < ch; ++c) {
      const float4* Ap = Ab + (size_t)c * 1024;
#pragma unroll
      for (int k = 0; k < 4; ++k) {
        float4 t = Ap[tid + k * 256];
        s[k].x += t.x; s[k].y += t.y; s[k].z += t.z; s[k].w += t.w;
      }
    }
#pragma unroll
    for (int k = 0; k < 4; ++k) {
      int idx = tid * 4 + k * 1024;
      int a = idx >> 6, b = idx & 63;
      SW[a][b] = s[k].x; SW[a][b + 1] = s[k].y; SW[a][b + 2] = s[k].z; SW[a][b + 3] = s[k].w;
    }
  }
  if (tid < 64) gl[tid] = g[h * L_SEQ + t0 + tid];
  __syncthreads();
  if (tid < 64) {
    // Gprev via 32-lane masked read + butterfly over the wave
    float gp = (tid < 32 && tid < ch) ? gsum[h * 32 + tid] : 0.f;
#pragma unroll
    for (int off = 32; off >= 1; off >>= 1) gp += __shfl_xor(gp, off, 64);
    float val = gl[tid];
#pragma unroll
    for (int off = 1; off < 64; off <<= 1) {
      float o = __shfl_up(val, (unsigned)off, 64);
      if (tid >= off) val += o;
    }
    Gs[tid] = fmaxf(gp + val, EPSF);
  }
  int lg = tid & 15, eg = tid >> 4;
  float acc[4][4] = {};
  // Phase A: carry = q @ Sprev
  for (int d = 0; d < 64; ++d) {
    float4 q4 = *(const float4*)(&qT[d][lg * 4]);
    float qv[4] = {q4.x, q4.y, q4.z, q4.w};
    float sv[4];
#pragma unroll
    for (int j = 0; j < 4; ++j) sv[j] = SW[d][eg * 4 + j];
#pragma unroll
    for (int r = 0; r < 4; ++r)
#pragma unroll
      for (int j = 0; j < 4; ++j)
        acc[r][j] = fmaf(qv[r], sv[j], acc[r][j]);
  }
  __syncthreads();
  // Phase B: scores -> gated causal weights (overwrite SW)
  float sc[4][4] = {};
  for (int d = 0; d < 64; ++d) {
    float4 q4 = *(const float4*)(&qT[d][lg * 4]);
    float4 v4 = *(const float4*)(&vb[d][eg * 4]);
    float qv[4] = {q4.x, q4.y, q4.z, q4.w};
    float vv[4] = {v4.x, v4.y, v4.z, v4.w};
#pragma unroll
    for (int r = 0; r < 4; ++r)
#pragma unroll
      for (int m = 0; m < 4; ++m)
        sc[r][m] = fmaf(qv[r], vv[m], sc[r][m]);
  }
#pragma unroll
  for (int r = 0; r < 4; ++r)
#pragma unroll
    for (int m = 0; m < 4; ++m) {
      int ll = lg * 4 + r, tt = eg * 4 + m;
      SW[ll][tt] = (tt <= ll) ? sc[r][m] * gl[tt] : 0.f;
    }
  __syncthreads();
  // Phase C: acc += w @ k_f^T
  for (int t = 0; t < 64; ++t) {
    float wv4[4], kv4[4];
#pragma unroll
    for (int r = 0; r < 4; ++r) wv4[r] = SW[lg * 4 + r][t];
#pragma unroll
    for (int j = 0; j < 4; ++j) kv4[j] = kb[eg * 4 + j][t];
#pragma unroll
    for (int r = 0; r < 4; ++r)
#pragma unroll
      for (int j = 0; j < 4; ++j)
        acc[r][j] = fmaf(wv4[r], kv4[j], acc[r][j]);
  }
  // epilogue: /G, l2norm over e (part2 reduce), bf16 store
  float val[4][4];
#pragma unroll
  for (int r = 0; r < 4; ++r) {
    float gi = 1.f / Gs[lg * 4 + r];
    float pr = 0.f;
#pragma unroll
    for (int j = 0; j < 4; ++j) { float v = acc[r][j] * gi; val[r][j] = v; pr = fmaf(v, v, pr); }
    part2[eg][lg * 4 + r] = pr;
  }
  __syncthreads();
  if (tid < 64) {
    float s = 0.f;
#pragma unroll
    for (int e = 0; e < 16; ++e) s += part2[e][tid];
    rsq[tid] = 1.f / fmaxf(sqrtf(s), EPSF);
  }
  __syncthreads();
#pragma unroll
  for (int r = 0; r < 4; ++r) {
    float inv = rsq[lg * 4 + r];
    union { ushort4 u; __hip_bfloat16 hh[4]; } pk;
#pragma unroll
    for (int j = 0; j < 4; ++j) pk.hh[j] = __float2bfloat16(val[r][j] * inv);
    *(ushort4*)(sp + (size_t)(t0 + lg * 4 + r) * D_MODEL + h * 64 + eg * 4) = pk.u;
  }
}

// ---------------- final GEMM: out = sp @ wo^T + b ----------------
__global__ __launch_bounds__(256) void gemm_out_kernel(const __hip_bfloat16* __restrict__ A,
    const __hip_bfloat16* __restrict__ W, const float* __restrict__ bias,
    float* __restrict__ O)
{
  const int N = D_MODEL, K = D_MODEL;
  int lane = threadIdx.x & 63;
  int wave = threadIdx.x >> 6;
  int m0 = blockIdx.x * 64 + wave * 16;
  int n0 = blockIdx.y * 64;
  int lrow = lane & 15, quad = lane >> 4;
  const __hip_bfloat16* Ap = A + (size_t)(m0 + lrow) * K + quad * 8;
  const __hip_bfloat16* Wp = W + (size_t)(n0 + lrow) * K + quad * 8;
  f32x4 acc[4] = {};
  for (int k0 = 0; k0 < K; k0 += 32) {
    short8 a = *(const short8*)(Ap + k0);
#pragma unroll
    for (int j = 0; j < 4; ++j) {
      short8 b = *(const short8*)(Wp + k0 + (size_t)j * 16 * K);
      acc[j] = __builtin_amdgcn_mfma_f32_16x16x32_bf16(a, b, acc[j], 0, 0, 0);
    }
  }
#pragma unroll
  for (int j = 0; j < 4; ++j) {
    int n = n0 + j * 16 + lrow;
    float bv = bias[n];
#pragma unroll
    for (int r = 0; r < 4; ++r)
      O[(size_t)(m0 + quad * 4 + r) * N + n] = acc[j][r] + bv;
  }
}

extern "C" void kernel_launch(void* const* d_in, const int* in_sizes, int n_in,
                              void* d_out, int out_size, void* d_ws, size_t ws_size,
                              hipStream_t stream) {
  const float* x = (const float*)d_in[0];
  const float* sb = (const float*)d_in[1];
  const float* wq_w = (const float*)d_in[2];
  const float* wq_b = (const float*)d_in[3];
  const float* wk_w = (const float*)d_in[4];
  const float* wk_b = (const float*)d_in[5];
  const float* wv_w = (const float*)d_in[6];
  const float* wv_b = (const float*)d_in[7];
  const float* wo_w = (const float*)d_in[8];
  const float* wo_b = (const float*)d_in[9];
  const float* td_w = (const float*)d_in[10];
  const float* td_b = (const float*)d_in[11];
  const float* wgz_w = (const float*)d_in[12];
  const float* wgz_b = (const float*)d_in[13];
  const float* kvs = (const float*)d_in[14];
  float* out = (float*)d_out;

  char* ws = (char*)d_ws;
  size_t off = 0;
  auto alloc = [&](size_t bytes) -> void* {
    void* p = ws + off;
    off += (bytes + 255) & ~(size_t)255;
    return p;
  };
  __hip_bfloat16* xb  = (__hip_bfloat16*)alloc((size_t)L_SEQ * D_MODEL * 2);
  __hip_bfloat16* sbb = (__hip_bfloat16*)alloc((size_t)L_SEQ * D_MODEL * 2);
  __hip_bfloat16* wqb = (__hip_bfloat16*)alloc((size_t)D_MODEL * D_MODEL * 2);
  __hip_bfloat16* wkb = (__hip_bfloat16*)alloc((size_t)D_MODEL * D_MODEL * 2);
  __hip_bfloat16* wvb = (__hip_bfloat16*)alloc((size_t)D_MODEL * D_MODEL * 2);
  __hip_bfloat16* tdb = (__hip_bfloat16*)alloc((size_t)D_MODEL * D_MODEL * 2);
  __hip_bfloat16* wob = (__hip_bfloat16*)alloc((size_t)D_MODEL * D_MODEL * 2);
  __hip_bfloat16* spb = (__hip_bfloat16*)alloc((size_t)L_SEQ * D_MODEL * 2);
  _Float16* ku16 = (_Float16*)alloc((size_t)D_MODEL * UPAD * 2);
  _Float16* vu16 = (_Float16*)alloc((size_t)D_MODEL * UPAD * 2);
  float* qbuf  = (float*)alloc((size_t)L_SEQ * D_MODEL * 4);
  float* fT    = (float*)alloc((size_t)D_MODEL * L_SEQ * 4);
  float* kfT   = (float*)alloc((size_t)D_MODEL * L_SEQ * 4);
  float* vfT   = (float*)alloc((size_t)D_MODEL * L_SEQ * 4);
  float* gbuf  = (float*)alloc((size_t)NH * L_SEQ * 4);
  float* gsum  = (float*)alloc((size_t)NH * 32 * 4);
  float* Abuf  = (float*)alloc((size_t)NH * 32 * 4096 * 4);

  prep_kernel<<<3584, 256, 0, stream>>>(x, sb, wq_w, wk_w, wv_w, td_w, wo_w,
                                        xb, sbb, wqb, wkb, wvb, tdb, wob,
                                        ku16, vu16);
  gemm4_kernel<<<dim3(L_SEQ / 64, D_MODEL / 64, 4), 256, 0, stream>>>(
      xb, sbb, wqb, wkb, wvb, tdb, wq_b, wk_b, wv_b, td_b, qbuf, fT,
      ku16, vu16);
  conv_kernel<<<512, 256, 0, stream>>>(ku16, vu16, fT, kfT, vfT);
  gatepart_kernel<<<dim3(32, 8), 256, 0, stream>>>(kfT, vfT, wgz_w, wgz_b, kvs, gbuf, Abuf, gsum);
  attn_kernel<<<dim3(32, 8), 256, 0, stream>>>(qbuf, kfT, vfT, gbuf, Abuf, gsum, spb);
  gemm_out_kernel<<<dim3(L_SEQ / 64, D_MODEL / 64), 256, 0, stream>>>(spb, wob, wo_b, out);
}